// Round 4
// baseline (774.870 us; speedup 1.0000x reference)
//
#include <hip/hip_runtime.h>
#include <math.h>

#define RGRID 128
#define NSTEPS 128
#define DATA_DIM 28

__device__ __forceinline__ float fast_rcp(float x) { return __builtin_amdgcn_rcpf(x); }

// One wave (64 lanes) per ray; lane = step-slot. Two outer iterations of 64 steps.
// Each lane trilerps its step's full 28-channel vector locally (8 corners,
// weighted-sum in registers -> no cross-lane corner reduction), does the SH dot,
// then a 64-lane affine scan composites the 64 steps:
//   per-step (a,b) = (1-alpha, alpha*c);  compose (a1,b1)∘(a2,b2) = (a1*a2, b1 + a1*b2)
__global__ __launch_bounds__(256) void render_kernel(
    const float* __restrict__ rays_o,
    const float* __restrict__ rays_d,
    const float* __restrict__ grid,
    const float* __restrict__ scaling,
    const float* __restrict__ offset,
    float* __restrict__ out, int N)
{
    int tid = blockIdx.x * blockDim.x + threadIdx.x;
    int ray = tid >> 6;
    int lane = tid & 63;
    if (ray >= N) return;

    float ox = rays_o[ray * 3 + 0], oy = rays_o[ray * 3 + 1], oz = rays_o[ray * 3 + 2];
    float rdx = rays_d[ray * 3 + 0], rdy = rays_d[ray * 3 + 1], rdz = rays_d[ray * 3 + 2];
    float sx = scaling[0], sy = scaling[1], sz = scaling[2];
    float fx = offset[0], fy = offset[1], fz = offset[2];

    float dn = rsqrtf(rdx * rdx + rdy * rdy + rdz * rdz);
    float dirx = rdx * dn, diry = rdy * dn, dirz = rdz * dn;

    float o0 = ox * sx + fx, o1 = oy * sy + fy, o2 = oz * sz + fz;
    float d0 = dirx * sx, d1 = diry * sy, d2 = dirz * sz;
    float delta_scale = rsqrtf(d0 * d0 + d1 * d1 + d2 * d2);

    float a0 = fabsf(d0) > 1e-9f ? d0 : 1e-9f;
    float a1 = fabsf(d1) > 1e-9f ? d1 : 1e-9f;
    float a2 = fabsf(d2) > 1e-9f ? d2 : 1e-9f;
    float i0 = 1.0f / a0, i1 = 1.0f / a1, i2 = 1.0f / a2;

    float t1x = (0.0f - o0) * i0, t2x = (1.0f - o0) * i0;
    float t1y = (0.0f - o1) * i1, t2y = (1.0f - o1) * i1;
    float t1z = (0.0f - o2) * i2, t2z = (1.0f - o2) * i2;
    float tmin = fmaxf(fmaxf(fminf(t1x, t2x), fminf(t1y, t2y)), fminf(t1z, t2z));
    tmin = fmaxf(tmin, 0.0f);
    float tmax = fminf(fminf(fmaxf(t1x, t2x), fmaxf(t1y, t2y)), fmaxf(t1z, t2z));
    bool valid = tmax > tmin;
    float dt = valid ? (tmax - tmin) * (1.0f / NSTEPS) : 0.0f;
    float sig_scale = dt * delta_scale;

    // SH basis (degree 2, 9 terms)
    const float C0 = 0.28209479177387814f;
    const float C1 = 0.4886025119029199f;
    float b0 = C0;
    float b1 = -C1 * diry;
    float b2 = C1 * dirz;
    float b3 = -C1 * dirx;
    float b4 = 1.0925484305920792f * dirx * diry;
    float b5 = -1.0925484305920792f * diry * dirz;
    float b6 = 0.31539156525252005f * (2.0f * dirz * dirz - dirx * dirx - diry * diry);
    float b7 = -1.0925484305920792f * dirx * dirz;
    float b8 = 0.5462742152960396f * (dirx * dirx - diry * diry);

    float T = 1.0f, accr = 0.0f, accg = 0.0f, accb = 0.0f;

    #pragma unroll
    for (int half = 0; half < 2; half++) {
        float t = tmin + ((float)(half * 64 + lane) + 0.5f) * dt;
        float px = o0 + t * d0, py = o1 + t * d1, pz = o2 + t * d2;

        float gx = px * (float)RGRID - 0.5f;
        float gy = py * (float)RGRID - 0.5f;
        float gz = pz * (float)RGRID - 0.5f;
        gx = fminf(fmaxf(gx, 0.0f), 126.9999f);
        gy = fminf(fmaxf(gy, 0.0f), 126.9999f);
        gz = fminf(fmaxf(gz, 0.0f), 126.9999f);

        float flx = floorf(gx), fly = floorf(gy), flz = floorf(gz);
        int ix = (int)flx, iy = (int)fly, iz = (int)flz;
        float wx = gx - flx, wy = gy - fly, wz = gz - flz;
        float ux = 1.0f - wx, uy = 1.0f - wy, uz = 1.0f - wz;

        // pairwise weight products
        float wxy00 = ux * uy, wxy01 = ux * wy, wxy10 = wx * uy, wxy11 = wx * wy;
        float w000 = wxy00 * uz, w001 = wxy00 * wz;
        float w010 = wxy01 * uz, w011 = wxy01 * wz;
        float w100 = wxy10 * uz, w101 = wxy10 * wz;
        float w110 = wxy11 * uz, w111 = wxy11 * wz;

        int voxbase = (ix * RGRID + iy) * RGRID + iz;
        const float* base = grid + (size_t)voxbase * DATA_DIM;

        float4 A0, A1, A2, A3, A4, A5, A6;

        // corner 000 initializes (mul), the rest FMA-accumulate
        {
            const float4* gp = (const float4*)(base);
            float4 u0 = gp[0], u1 = gp[1], u2 = gp[2], u3 = gp[3], u4 = gp[4], u5 = gp[5], u6 = gp[6];
            float w = w000;
            A0.x = w*u0.x; A0.y = w*u0.y; A0.z = w*u0.z; A0.w = w*u0.w;
            A1.x = w*u1.x; A1.y = w*u1.y; A1.z = w*u1.z; A1.w = w*u1.w;
            A2.x = w*u2.x; A2.y = w*u2.y; A2.z = w*u2.z; A2.w = w*u2.w;
            A3.x = w*u3.x; A3.y = w*u3.y; A3.z = w*u3.z; A3.w = w*u3.w;
            A4.x = w*u4.x; A4.y = w*u4.y; A4.z = w*u4.z; A4.w = w*u4.w;
            A5.x = w*u5.x; A5.y = w*u5.y; A5.z = w*u5.z; A5.w = w*u5.w;
            A6.x = w*u6.x; A6.y = w*u6.y; A6.z = w*u6.z; A6.w = w*u6.w;
        }
        #define ACC_CORNER(VOXOFF, W) { \
            const float4* gp = (const float4*)(base + (VOXOFF) * DATA_DIM); \
            float4 u0 = gp[0], u1 = gp[1], u2 = gp[2], u3 = gp[3], u4 = gp[4], u5 = gp[5], u6 = gp[6]; \
            float w = (W); \
            A0.x = fmaf(w, u0.x, A0.x); A0.y = fmaf(w, u0.y, A0.y); A0.z = fmaf(w, u0.z, A0.z); A0.w = fmaf(w, u0.w, A0.w); \
            A1.x = fmaf(w, u1.x, A1.x); A1.y = fmaf(w, u1.y, A1.y); A1.z = fmaf(w, u1.z, A1.z); A1.w = fmaf(w, u1.w, A1.w); \
            A2.x = fmaf(w, u2.x, A2.x); A2.y = fmaf(w, u2.y, A2.y); A2.z = fmaf(w, u2.z, A2.z); A2.w = fmaf(w, u2.w, A2.w); \
            A3.x = fmaf(w, u3.x, A3.x); A3.y = fmaf(w, u3.y, A3.y); A3.z = fmaf(w, u3.z, A3.z); A3.w = fmaf(w, u3.w, A3.w); \
            A4.x = fmaf(w, u4.x, A4.x); A4.y = fmaf(w, u4.y, A4.y); A4.z = fmaf(w, u4.z, A4.z); A4.w = fmaf(w, u4.w, A4.w); \
            A5.x = fmaf(w, u5.x, A5.x); A5.y = fmaf(w, u5.y, A5.y); A5.z = fmaf(w, u5.z, A5.z); A5.w = fmaf(w, u5.w, A5.w); \
            A6.x = fmaf(w, u6.x, A6.x); A6.y = fmaf(w, u6.y, A6.y); A6.z = fmaf(w, u6.z, A6.z); A6.w = fmaf(w, u6.w, A6.w); \
        }
        ACC_CORNER(1,             w001);
        ACC_CORNER(RGRID,         w010);
        ACC_CORNER(RGRID + 1,     w011);
        ACC_CORNER(RGRID*RGRID,         w100);
        ACC_CORNER(RGRID*RGRID + 1,     w101);
        ACC_CORNER(RGRID*RGRID + RGRID,     w110);
        ACC_CORNER(RGRID*RGRID + RGRID + 1, w111);
        #undef ACC_CORNER

        // SH dot: ch 0..8 red, 9..17 green, 18..26 blue, 27 sigma
        float vr = b0*A0.x + b1*A0.y + b2*A0.z + b3*A0.w
                 + b4*A1.x + b5*A1.y + b6*A1.z + b7*A1.w + b8*A2.x;
        float vg = b0*A2.y + b1*A2.z + b2*A2.w
                 + b3*A3.x + b4*A3.y + b5*A3.z + b6*A3.w
                 + b7*A4.x + b8*A4.y;
        float vb = b0*A4.z + b1*A4.w
                 + b2*A5.x + b3*A5.y + b4*A5.z + b5*A5.w
                 + b6*A6.x + b7*A6.y + b8*A6.z;
        float vs = A6.w;

        // per-step affine transform
        float sigma = valid ? fmaxf(vs, 0.0f) : 0.0f;
        float alpha = 1.0f - __expf(-sigma * sig_scale);
        float av = 1.0f - alpha;
        float br = alpha * fast_rcp(1.0f + __expf(-vr));
        float bg = alpha * fast_rcp(1.0f + __expf(-vg));
        float bb = alpha * fast_rcp(1.0f + __expf(-vb));

        // inclusive affine scan across all 64 lanes (lane index == step index)
        #pragma unroll
        for (int d = 1; d < 64; d <<= 1) {
            float pa  = __shfl_up(av, d);
            float pbr = __shfl_up(br, d);
            float pbg = __shfl_up(bg, d);
            float pbb = __shfl_up(bb, d);
            if (lane >= d) {
                br = pbr + pa * br;
                bg = pbg + pa * bg;
                bb = pbb + pa * bb;
                av = pa * av;
            }
        }

        // lane 63 holds the 64-step composite; fold into carried state
        float ca  = __shfl(av, 63);
        float cbr = __shfl(br, 63);
        float cbg = __shfl(bg, 63);
        float cbb = __shfl(bb, 63);
        accr += T * cbr;
        accg += T * cbg;
        accb += T * cbb;
        T *= ca;
    }

    if (lane == 0) {
        out[ray * 3 + 0] = accr + T * 1.0f;  // BG = 1.0
        out[ray * 3 + 1] = accg + T * 1.0f;
        out[ray * 3 + 2] = accb + T * 1.0f;
    }
}

extern "C" void kernel_launch(void* const* d_in, const int* in_sizes, int n_in,
                              void* d_out, int out_size, void* d_ws, size_t ws_size,
                              hipStream_t stream) {
    const float* rays_o  = (const float*)d_in[0];
    const float* rays_d  = (const float*)d_in[1];
    const float* grid    = (const float*)d_in[2];
    const float* scaling = (const float*)d_in[3];
    const float* offset  = (const float*)d_in[4];
    float* out = (float*)d_out;
    int N = in_sizes[0] / 3;  // 32768 rays

    int threads = 256;                 // 4 waves = 4 rays per block
    long long total = (long long)N * 64;
    int blocks = (int)((total + threads - 1) / threads);
    render_kernel<<<blocks, threads, 0, stream>>>(rays_o, rays_d, grid, scaling, offset, out, N);
}

// Round 5
// 583.221 us; speedup vs baseline: 1.3286x; 1.3286x over previous
//
#include <hip/hip_runtime.h>
#include <math.h>

#define RGRID 128
#define NSTEPS 128
#define DATA_DIM 28

__device__ __forceinline__ float fast_rcp(float x) { return __builtin_amdgcn_rcpf(x); }

// ---------------- Phase 0: per-ray parameters (80 B/ray into ws) ----------------
__global__ __launch_bounds__(256) void ray_setup_kernel(
    const float* __restrict__ rays_o,
    const float* __restrict__ rays_d,
    const float* __restrict__ scaling,
    const float* __restrict__ offset,
    float* __restrict__ params, int N)
{
    int ray = blockIdx.x * blockDim.x + threadIdx.x;
    if (ray >= N) return;

    float ox = rays_o[ray * 3 + 0], oy = rays_o[ray * 3 + 1], oz = rays_o[ray * 3 + 2];
    float rdx = rays_d[ray * 3 + 0], rdy = rays_d[ray * 3 + 1], rdz = rays_d[ray * 3 + 2];
    float sx = scaling[0], sy = scaling[1], sz = scaling[2];
    float fx = offset[0], fy = offset[1], fz = offset[2];

    float dn = rsqrtf(rdx * rdx + rdy * rdy + rdz * rdz);
    float dirx = rdx * dn, diry = rdy * dn, dirz = rdz * dn;

    float o0 = ox * sx + fx, o1 = oy * sy + fy, o2 = oz * sz + fz;
    float d0 = dirx * sx, d1 = diry * sy, d2 = dirz * sz;
    float delta_scale = rsqrtf(d0 * d0 + d1 * d1 + d2 * d2);

    float a0 = fabsf(d0) > 1e-9f ? d0 : 1e-9f;
    float a1 = fabsf(d1) > 1e-9f ? d1 : 1e-9f;
    float a2 = fabsf(d2) > 1e-9f ? d2 : 1e-9f;
    float i0 = 1.0f / a0, i1 = 1.0f / a1, i2 = 1.0f / a2;

    float t1x = (0.0f - o0) * i0, t2x = (1.0f - o0) * i0;
    float t1y = (0.0f - o1) * i1, t2y = (1.0f - o1) * i1;
    float t1z = (0.0f - o2) * i2, t2z = (1.0f - o2) * i2;
    float tmin = fmaxf(fmaxf(fminf(t1x, t2x), fminf(t1y, t2y)), fminf(t1z, t2z));
    tmin = fmaxf(tmin, 0.0f);
    float tmax = fminf(fminf(fmaxf(t1x, t2x), fmaxf(t1y, t2y)), fmaxf(t1z, t2z));
    bool valid = tmax > tmin;
    float dt = valid ? (tmax - tmin) * (1.0f / NSTEPS) : 0.0f;
    float sig_scale = dt * delta_scale;

    const float C1 = 0.4886025119029199f;
    float b1 = -C1 * diry;
    float b2 = C1 * dirz;
    float b3 = -C1 * dirx;
    float b4 = 1.0925484305920792f * dirx * diry;
    float b5 = -1.0925484305920792f * diry * dirz;
    float b6 = 0.31539156525252005f * (2.0f * dirz * dirz - dirx * dirx - diry * diry);
    float b7 = -1.0925484305920792f * dirx * dirz;
    float b8 = 0.5462742152960396f * (dirx * dirx - diry * diry);

    float4* P = (float4*)(params + (size_t)ray * 20);
    P[0] = make_float4(o0, o1, o2, tmin);
    P[1] = make_float4(d0, d1, d2, dt);
    P[2] = make_float4(b1, b2, b3, b4);
    P[3] = make_float4(b5, b6, b7, b8);
    P[4] = make_float4(sig_scale, valid ? 1.0f : 0.0f, 0.0f, 0.0f);
}

// ---------------- Phase 1: fully-parallel per-step sampling ----------------
// One wave per (ray, octet-of-8-steps); lane = s*8+c, s=step-in-octet, c=corner.
// No loop, no scan, no carried state -> every wave independent.
__global__ __launch_bounds__(256) void sample_kernel(
    const float* __restrict__ grid,
    const float* __restrict__ params,
    float* __restrict__ seg, int N)
{
    int tid = blockIdx.x * blockDim.x + threadIdx.x;
    int unit = tid >> 6;        // (ray, octet)
    int lane = tid & 63;
    int ray = unit >> 4;
    int octet = unit & 15;
    if (ray >= N) return;
    int s = lane >> 3;
    int c = lane & 7;

    const float4* P = (const float4*)(params + (size_t)ray * 20);
    float4 p0 = P[0], p1 = P[1], p2 = P[2], p3 = P[3], p4 = P[4];
    float o0 = p0.x, o1 = p0.y, o2 = p0.z, tmin = p0.w;
    float d0 = p1.x, d1 = p1.y, d2 = p1.z, dt = p1.w;
    float b1 = p2.x, b2 = p2.y, b3 = p2.z, b4 = p2.w;
    float b5 = p3.x, b6 = p3.y, b7 = p3.z, b8 = p3.w;
    float sig_scale = p4.x;
    bool valid = p4.y != 0.0f;
    const float b0 = 0.28209479177387814f;

    int cdx = (c >> 2) & 1, cdy = (c >> 1) & 1, cdz = c & 1;
    int laneoff = (cdx << 14) + (cdy << 7) + cdz;
    float fsx = cdx ? 1.0f : -1.0f, fbx = cdx ? 0.0f : 1.0f;
    float fsy = cdy ? 1.0f : -1.0f, fby = cdy ? 0.0f : 1.0f;
    float fsz = cdz ? 1.0f : -1.0f, fbz = cdz ? 0.0f : 1.0f;

    int gstep = octet * 8 + s;
    float t = tmin + ((float)gstep + 0.5f) * dt;
    float px = o0 + t * d0, py = o1 + t * d1, pz = o2 + t * d2;

    float gx = px * (float)RGRID - 0.5f;
    float gy = py * (float)RGRID - 0.5f;
    float gz = pz * (float)RGRID - 0.5f;
    gx = fminf(fmaxf(gx, 0.0f), 126.9999f);
    gy = fminf(fmaxf(gy, 0.0f), 126.9999f);
    gz = fminf(fmaxf(gz, 0.0f), 126.9999f);

    float flx = floorf(gx), fly = floorf(gy), flz = floorf(gz);
    int ix = (int)flx, iy = (int)fly, iz = (int)flz;
    float wx = gx - flx, wy = gy - fly, wz = gz - flz;

    float wgt = (fsx * wx + fbx) * (fsy * wy + fby) * (fsz * wz + fbz);

    int vox = (ix << 14) + (iy << 7) + iz + laneoff;
    const float4* gp = (const float4*)(grid + (size_t)vox * DATA_DIM);
    float4 v0 = gp[0], v1 = gp[1], v2 = gp[2], v3 = gp[3], v4 = gp[4], v5 = gp[5], v6 = gp[6];

    // channels 0..8 red SH, 9..17 green, 18..26 blue, 27 sigma
    float vr = b0 * v0.x + b1 * v0.y + b2 * v0.z + b3 * v0.w
             + b4 * v1.x + b5 * v1.y + b6 * v1.z + b7 * v1.w + b8 * v2.x;
    float vg = b0 * v2.y + b1 * v2.z + b2 * v2.w
             + b3 * v3.x + b4 * v3.y + b5 * v3.z + b6 * v3.w
             + b7 * v4.x + b8 * v4.y;
    float vb = b0 * v4.z + b1 * v4.w
             + b2 * v5.x + b3 * v5.y + b4 * v5.z + b5 * v5.w
             + b6 * v6.x + b7 * v6.y + b8 * v6.z;
    float vs = v6.w;

    vr *= wgt; vg *= wgt; vb *= wgt; vs *= wgt;

    // corner reduce within each step's 8-lane group
    #pragma unroll
    for (int m = 1; m < 8; m <<= 1) {
        vr += __shfl_xor(vr, m);
        vg += __shfl_xor(vg, m);
        vb += __shfl_xor(vb, m);
        vs += __shfl_xor(vs, m);
    }

    float sigma = valid ? fmaxf(vs, 0.0f) : 0.0f;
    float alpha = 1.0f - __expf(-sigma * sig_scale);
    float av = 1.0f - alpha;
    float br = alpha * fast_rcp(1.0f + __expf(-vr));
    float bg = alpha * fast_rcp(1.0f + __expf(-vg));
    float bb = alpha * fast_rcp(1.0f + __expf(-vb));

    // lanes c<4 of each step-group write (av, br, bg, bb) -> 128B/wave, coalesced
    float v = (c == 0) ? av : ((c == 1) ? br : ((c == 2) ? bg : bb));
    if (c < 4) seg[(size_t)ray * (NSTEPS * 4) + gstep * 4 + c] = v;
}

// ---------------- Phase 2: per-ray affine scan composite ----------------
__global__ __launch_bounds__(256) void composite_kernel(
    const float* __restrict__ seg,
    float* __restrict__ out, int N)
{
    int tid = blockIdx.x * blockDim.x + threadIdx.x;
    int ray = tid >> 6;
    int lane = tid & 63;
    if (ray >= N) return;

    float T = 1.0f, accr = 0.0f, accg = 0.0f, accb = 0.0f;
    const float4* sp = (const float4*)(seg + (size_t)ray * (NSTEPS * 4));

    #pragma unroll
    for (int half = 0; half < 2; half++) {
        float4 v = sp[half * 64 + lane];
        float av = v.x, br = v.y, bg = v.z, bb = v.w;

        // inclusive affine scan across 64 lanes (lane == step)
        #pragma unroll
        for (int d = 1; d < 64; d <<= 1) {
            float pa  = __shfl_up(av, d);
            float pbr = __shfl_up(br, d);
            float pbg = __shfl_up(bg, d);
            float pbb = __shfl_up(bb, d);
            if (lane >= d) {
                br = pbr + pa * br;
                bg = pbg + pa * bg;
                bb = pbb + pa * bb;
                av = pa * av;
            }
        }
        float ca  = __shfl(av, 63);
        float cbr = __shfl(br, 63);
        float cbg = __shfl(bg, 63);
        float cbb = __shfl(bb, 63);
        accr += T * cbr;
        accg += T * cbg;
        accb += T * cbb;
        T *= ca;
    }

    if (lane == 0) {
        out[ray * 3 + 0] = accr + T * 1.0f;  // BG = 1.0
        out[ray * 3 + 1] = accg + T * 1.0f;
        out[ray * 3 + 2] = accb + T * 1.0f;
    }
}

// ---------------- Fallback: R3 monolithic (if ws too small) ----------------
__global__ __launch_bounds__(256) void render_kernel(
    const float* __restrict__ rays_o,
    const float* __restrict__ rays_d,
    const float* __restrict__ grid,
    const float* __restrict__ scaling,
    const float* __restrict__ offset,
    float* __restrict__ out, int N)
{
    int tid = blockIdx.x * blockDim.x + threadIdx.x;
    int ray = tid >> 6;
    int lane = tid & 63;
    int s = lane >> 3;
    int c = lane & 7;
    if (ray >= N) return;

    float ox = rays_o[ray * 3 + 0], oy = rays_o[ray * 3 + 1], oz = rays_o[ray * 3 + 2];
    float rdx = rays_d[ray * 3 + 0], rdy = rays_d[ray * 3 + 1], rdz = rays_d[ray * 3 + 2];
    float sx = scaling[0], sy = scaling[1], sz = scaling[2];
    float fx = offset[0], fy = offset[1], fz = offset[2];

    float dn = rsqrtf(rdx * rdx + rdy * rdy + rdz * rdz);
    float dirx = rdx * dn, diry = rdy * dn, dirz = rdz * dn;

    float o0 = ox * sx + fx, o1 = oy * sy + fy, o2 = oz * sz + fz;
    float d0 = dirx * sx, d1 = diry * sy, d2 = dirz * sz;
    float delta_scale = rsqrtf(d0 * d0 + d1 * d1 + d2 * d2);

    float a0 = fabsf(d0) > 1e-9f ? d0 : 1e-9f;
    float a1 = fabsf(d1) > 1e-9f ? d1 : 1e-9f;
    float a2 = fabsf(d2) > 1e-9f ? d2 : 1e-9f;
    float i0 = 1.0f / a0, i1 = 1.0f / a1, i2 = 1.0f / a2;

    float t1x = (0.0f - o0) * i0, t2x = (1.0f - o0) * i0;
    float t1y = (0.0f - o1) * i1, t2y = (1.0f - o1) * i1;
    float t1z = (0.0f - o2) * i2, t2z = (1.0f - o2) * i2;
    float tmin = fmaxf(fmaxf(fminf(t1x, t2x), fminf(t1y, t2y)), fminf(t1z, t2z));
    tmin = fmaxf(tmin, 0.0f);
    float tmax = fminf(fminf(fmaxf(t1x, t2x), fmaxf(t1y, t2y)), fmaxf(t1z, t2z));
    bool valid = tmax > tmin;
    float dt = valid ? (tmax - tmin) * (1.0f / NSTEPS) : 0.0f;
    float sig_scale = dt * delta_scale;

    const float C0 = 0.28209479177387814f;
    const float C1 = 0.4886025119029199f;
    float b0 = C0;
    float b1 = -C1 * diry;
    float b2 = C1 * dirz;
    float b3 = -C1 * dirx;
    float b4 = 1.0925484305920792f * dirx * diry;
    float b5 = -1.0925484305920792f * diry * dirz;
    float b6 = 0.31539156525252005f * (2.0f * dirz * dirz - dirx * dirx - diry * diry);
    float b7 = -1.0925484305920792f * dirx * dirz;
    float b8 = 0.5462742152960396f * (dirx * dirx - diry * diry);

    int cdx = (c >> 2) & 1, cdy = (c >> 1) & 1, cdz = c & 1;
    int laneoff = (cdx << 14) + (cdy << 7) + cdz;
    float fsx = cdx ? 1.0f : -1.0f, fbx = cdx ? 0.0f : 1.0f;
    float fsy = cdy ? 1.0f : -1.0f, fby = cdy ? 0.0f : 1.0f;
    float fsz = cdz ? 1.0f : -1.0f, fbz = cdz ? 0.0f : 1.0f;

    float T = 1.0f, accr = 0.0f, accg = 0.0f, accb = 0.0f;
    float soff = (float)s + 0.5f;

    for (int it = 0; it < NSTEPS / 8; it++) {
        float t = tmin + ((float)(it * 8) + soff) * dt;
        float px = o0 + t * d0, py = o1 + t * d1, pz = o2 + t * d2;

        float gx = px * (float)RGRID - 0.5f;
        float gy = py * (float)RGRID - 0.5f;
        float gz = pz * (float)RGRID - 0.5f;
        gx = fminf(fmaxf(gx, 0.0f), 126.9999f);
        gy = fminf(fmaxf(gy, 0.0f), 126.9999f);
        gz = fminf(fmaxf(gz, 0.0f), 126.9999f);

        float flx = floorf(gx), fly = floorf(gy), flz = floorf(gz);
        int ix = (int)flx, iy = (int)fly, iz = (int)flz;
        float wx = gx - flx, wy = gy - fly, wz = gz - flz;

        float wgt = (fsx * wx + fbx) * (fsy * wy + fby) * (fsz * wz + fbz);

        int vox = (ix << 14) + (iy << 7) + iz + laneoff;
        const float4* gp = (const float4*)(grid + (size_t)vox * DATA_DIM);
        float4 v0 = gp[0], v1 = gp[1], v2 = gp[2], v3 = gp[3], v4 = gp[4], v5 = gp[5], v6 = gp[6];

        float vr = b0 * v0.x + b1 * v0.y + b2 * v0.z + b3 * v0.w
                 + b4 * v1.x + b5 * v1.y + b6 * v1.z + b7 * v1.w + b8 * v2.x;
        float vg = b0 * v2.y + b1 * v2.z + b2 * v2.w
                 + b3 * v3.x + b4 * v3.y + b5 * v3.z + b6 * v3.w
                 + b7 * v4.x + b8 * v4.y;
        float vb = b0 * v4.z + b1 * v4.w
                 + b2 * v5.x + b3 * v5.y + b4 * v5.z + b5 * v5.w
                 + b6 * v6.x + b7 * v6.y + b8 * v6.z;
        float vs = v6.w;

        vr *= wgt; vg *= wgt; vb *= wgt; vs *= wgt;

        #pragma unroll
        for (int m = 1; m < 8; m <<= 1) {
            vr += __shfl_xor(vr, m);
            vg += __shfl_xor(vg, m);
            vb += __shfl_xor(vb, m);
            vs += __shfl_xor(vs, m);
        }

        float sigma = valid ? fmaxf(vs, 0.0f) : 0.0f;
        float alpha = 1.0f - __expf(-sigma * sig_scale);
        float av = 1.0f - alpha;
        float br = alpha * fast_rcp(1.0f + __expf(-vr));
        float bg = alpha * fast_rcp(1.0f + __expf(-vg));
        float bb = alpha * fast_rcp(1.0f + __expf(-vb));

        #pragma unroll
        for (int d = 8; d < 64; d <<= 1) {
            float pa  = __shfl_up(av, d);
            float pbr = __shfl_up(br, d);
            float pbg = __shfl_up(bg, d);
            float pbb = __shfl_up(bb, d);
            if (lane >= d) {
                br = pbr + pa * br;
                bg = pbg + pa * bg;
                bb = pbb + pa * bb;
                av = pa * av;
            }
        }

        float ca  = __shfl(av, 63);
        float cbr = __shfl(br, 63);
        float cbg = __shfl(bg, 63);
        float cbb = __shfl(bb, 63);
        accr += T * cbr;
        accg += T * cbg;
        accb += T * cbb;
        T *= ca;
    }

    if (lane == 0) {
        out[ray * 3 + 0] = accr + T * 1.0f;
        out[ray * 3 + 1] = accg + T * 1.0f;
        out[ray * 3 + 2] = accb + T * 1.0f;
    }
}

extern "C" void kernel_launch(void* const* d_in, const int* in_sizes, int n_in,
                              void* d_out, int out_size, void* d_ws, size_t ws_size,
                              hipStream_t stream) {
    const float* rays_o  = (const float*)d_in[0];
    const float* rays_d  = (const float*)d_in[1];
    const float* grid    = (const float*)d_in[2];
    const float* scaling = (const float*)d_in[3];
    const float* offset  = (const float*)d_in[4];
    float* out = (float*)d_out;
    int N = in_sizes[0] / 3;  // 32768 rays

    size_t seg_floats = (size_t)N * NSTEPS * 4;
    size_t par_floats = (size_t)N * 20;
    size_t need = (seg_floats + par_floats) * sizeof(float);

    if (ws_size >= need) {
        float* seg = (float*)d_ws;
        float* params = seg + seg_floats;

        ray_setup_kernel<<<(N + 255) / 256, 256, 0, stream>>>(
            rays_o, rays_d, scaling, offset, params, N);

        long long th1 = (long long)N * 16 * 64;
        sample_kernel<<<(int)((th1 + 255) / 256), 256, 0, stream>>>(
            grid, params, seg, N);

        long long th2 = (long long)N * 64;
        composite_kernel<<<(int)((th2 + 255) / 256), 256, 0, stream>>>(seg, out, N);
    } else {
        long long total = (long long)N * 64;
        int blocks = (int)((total + 255) / 256);
        render_kernel<<<blocks, 256, 0, stream>>>(rays_o, rays_d, grid, scaling, offset, out, N);
    }
}